// Round 4
// baseline (513.300 us; speedup 1.0000x reference)
//
#include <hip/hip_runtime.h>

#define FEAT 128

typedef _Float16 half8 __attribute__((ext_vector_type(8)));
typedef _Float16 half4v __attribute__((ext_vector_type(4)));
typedef float f32x4 __attribute__((ext_vector_type(4)));

// ---------- zero: clear degS/degD (contiguous) ----------
__global__ __launch_bounds__(256) void zero_kernel(int4* __restrict__ p, int cnt4) {
    int i = blockIdx.x * 256 + threadIdx.x;
    if (i < cnt4) p[i] = make_int4(0, 0, 0, 0);
}

// ---------- degree count via global atomics (L2-resident counters) ----------
__global__ __launch_bounds__(256) void deg_kernel(const int* __restrict__ src,
                                                  const int* __restrict__ dst,
                                                  int* __restrict__ degS,
                                                  int* __restrict__ degD, int E) {
    int e = blockIdx.x * 256 + threadIdx.x;
    if (e < E) {
        atomicAdd(&degS[src[e]], 1);
        atomicAdd(&degD[dst[e]], 1);
    }
}

// ---------- scan phase 1: block sums + norms ----------
__global__ __launch_bounds__(256) void scan1_kernel(const int* __restrict__ degD,
                                                    const int* __restrict__ degS,
                                                    int* __restrict__ blockSums,
                                                    float* __restrict__ ns,
                                                    float* __restrict__ nd, int n) {
    __shared__ int buf[256];
    int tid = threadIdx.x;
    int v = blockIdx.x * 256 + tid;
    int s = degD[v];
    if (v < n) {
        int o = degS[v];
        ns[v] = 1.0f / sqrtf((float)(o < 1 ? 1 : o));
        nd[v] = 1.0f / sqrtf((float)(s < 1 ? 1 : s));
    }
    buf[tid] = s;
    __syncthreads();
    #pragma unroll
    for (int off = 1; off < 256; off <<= 1) {
        int t = (tid >= off) ? buf[tid - off] : 0;
        __syncthreads();
        buf[tid] += t;
        __syncthreads();
    }
    if (tid == 255) blockSums[blockIdx.x] = buf[255];
}

// ---------- scan phase 2 ----------
__global__ __launch_bounds__(256) void scan2_kernel(const int* __restrict__ blockSums,
                                                    int* __restrict__ blockOffs, int nb) {
    __shared__ int buf[256];
    int tid = threadIdx.x;
    int v = (tid < nb) ? blockSums[tid] : 0;
    buf[tid] = v;
    __syncthreads();
    #pragma unroll
    for (int off = 1; off < 256; off <<= 1) {
        int t = (tid >= off) ? buf[tid - off] : 0;
        __syncthreads();
        buf[tid] += t;
        __syncthreads();
    }
    if (tid < nb) blockOffs[tid] = buf[tid] - v;
}

// ---------- scan phase 3: offsets + atomic cursors ----------
__global__ __launch_bounds__(256) void scan3_kernel(const int* __restrict__ degD,
                                                    const int* __restrict__ blockOffs,
                                                    int* __restrict__ offsc,
                                                    int* __restrict__ gcursor, int n) {
    __shared__ int buf[256];
    int tid = threadIdx.x;
    int v = blockIdx.x * 256 + tid;
    int s = degD[v];
    buf[tid] = s;
    __syncthreads();
    #pragma unroll
    for (int off = 1; off < 256; off <<= 1) {
        int t = (tid >= off) ? buf[tid - off] : 0;
        __syncthreads();
        buf[tid] += t;
        __syncthreads();
    }
    int o = blockOffs[blockIdx.x] + buf[tid] - s;
    if (v <= n) offsc[v] = o;          // pad nodes have zero degree -> v==n gets total E
    gcursor[v] = o;
}

// ---------- fill: atomic scatter (nondeterministic order; sums are tolerance-safe) ----------
__global__ __launch_bounds__(256) void fill_kernel(const int* __restrict__ src,
                                                   const int* __restrict__ dst,
                                                   int* __restrict__ gcursor,
                                                   int* __restrict__ esrc, int E) {
    int e = blockIdx.x * 256 + threadIdx.x;
    if (e < E) {
        int p = atomicAdd(&gcursor[dst[e]], 1);
        esrc[p] = src[e];
    }
}

// ---------- prescale: xh = fp16(in_feat * ns) ----------
__global__ void prescale_kernel(const float* __restrict__ x, const float* __restrict__ ns,
                                _Float16* __restrict__ xh, int n) {
    int i = blockIdx.x * blockDim.x + threadIdx.x;   // one thread per 8 elements
    if (i >= n * (FEAT / 8)) return;
    int v = i >> 4;
    float w = ns[v];
    float4 t0 = ((const float4*)x)[i * 2];
    float4 t1 = ((const float4*)x)[i * 2 + 1];
    half8 h;
    h[0] = (_Float16)(t0.x * w); h[1] = (_Float16)(t0.y * w);
    h[2] = (_Float16)(t0.z * w); h[3] = (_Float16)(t0.w * w);
    h[4] = (_Float16)(t1.x * w); h[5] = (_Float16)(t1.y * w);
    h[6] = (_Float16)(t1.z * w); h[7] = (_Float16)(t1.w * w);
    ((float4*)xh)[i] = __builtin_bit_cast(float4, h);
}

// ---------- W prep: fp16 value+residual, transposed to [col][k] ----------
__global__ __launch_bounds__(256) void wprep_kernel(const float* __restrict__ Wa,
                                                    const float* __restrict__ Wb,
                                                    const float* __restrict__ Wc,
                                                    const float* __restrict__ Wd,
                                                    const float* __restrict__ We,
                                                    _Float16* __restrict__ w16t,
                                                    _Float16* __restrict__ wrt) {
    int gid = blockIdx.x * 256 + threadIdx.x;        // 5 * 128 * 128 = 81920
    int l = gid >> 14;
    int idx = gid & 16383;
    int col = idx >> 7;
    int k = idx & 127;
    const float* Wp = (l == 0) ? Wa : (l == 1) ? Wb : (l == 2) ? Wc : (l == 3) ? Wd : We;
    float w = Wp[k * FEAT + col];
    _Float16 h = (_Float16)w;
    _Float16 r = (_Float16)(w - (float)h);
    w16t[gid] = h;
    wrt[gid] = r;
}

// ---------- aggregation: 2 nodes per wave, fp16 gather, fp32 accumulate ----------
__global__ __launch_bounds__(256) void agg_kernel(const _Float16* __restrict__ x,
                                                  const int* __restrict__ offs,
                                                  const int* __restrict__ esrc,
                                                  const float* __restrict__ nd,
                                                  float* __restrict__ m, int n) {
    int gid = blockIdx.x * 256 + threadIdx.x;
    int v = gid >> 5;                      // one 32-thread half-wave per node
    if (v >= n) return;
    int lane = threadIdx.x & 31;
    int q = lane >> 4;       // stream 0/1 within the node (stride 2)
    int c = lane & 15;       // 16 lanes x 16B cover a 128-half row
    int s0 = offs[v], s1 = offs[v + 1];
    float a0[8] = {0,0,0,0,0,0,0,0};
    float a1[8] = {0,0,0,0,0,0,0,0};
    float a2[8] = {0,0,0,0,0,0,0,0};
    float a3[8] = {0,0,0,0,0,0,0,0};
    int j = s0 + q;
    // 4 edges per stream in flight -> 4 row-loads outstanding per lane
    for (; j + 6 < s1; j += 8) {
        int e0 = esrc[j], e1 = esrc[j + 2], e2 = esrc[j + 4], e3 = esrc[j + 6];
        float4 r0 = ((const float4*)(x + (size_t)e0 * FEAT))[c];
        float4 r1 = ((const float4*)(x + (size_t)e1 * FEAT))[c];
        float4 r2 = ((const float4*)(x + (size_t)e2 * FEAT))[c];
        float4 r3 = ((const float4*)(x + (size_t)e3 * FEAT))[c];
        half8 h0 = __builtin_bit_cast(half8, r0);
        half8 h1 = __builtin_bit_cast(half8, r1);
        half8 h2 = __builtin_bit_cast(half8, r2);
        half8 h3 = __builtin_bit_cast(half8, r3);
        #pragma unroll
        for (int k = 0; k < 8; ++k) {
            a0[k] += (float)h0[k];
            a1[k] += (float)h1[k];
            a2[k] += (float)h2[k];
            a3[k] += (float)h3[k];
        }
    }
    for (; j < s1; j += 2) {
        int e0 = esrc[j];
        float4 r0 = ((const float4*)(x + (size_t)e0 * FEAT))[c];
        half8 h0 = __builtin_bit_cast(half8, r0);
        #pragma unroll
        for (int k = 0; k < 8; ++k) a0[k] += (float)h0[k];
    }
    float r[8];
    #pragma unroll
    for (int k = 0; k < 8; ++k) r[k] = (a0[k] + a1[k]) + (a2[k] + a3[k]);
    #pragma unroll
    for (int k = 0; k < 8; ++k) r[k] += __shfl_xor(r[k], 16);   // cross-stream, stays in half-wave
    if (q == 0) {
        float sc = nd[v];
        float4 o0, o1;
        o0.x = r[0] * sc; o0.y = r[1] * sc; o0.z = r[2] * sc; o0.w = r[3] * sc;
        o1.x = r[4] * sc; o1.y = r[5] * sc; o1.z = r[6] * sc; o1.w = r[7] * sc;
        ((float4*)(m + (size_t)v * FEAT))[c * 2] = o0;
        ((float4*)(m + (size_t)v * FEAT))[c * 2 + 1] = o1;
    }
}

// ---------- GEMM: MFMA f16 value+residual, 64x128 tile, 512 threads (8 waves) ----------
// acc = A16*W16 + A16*Wr + Ar*W16  (drops Ar*Wr ~ 2.4e-7 rel); 96KB LDS -> 1 block/CU.
template<int MODE>   // 0: relu*ns -> fp16   1: last layer (fp32 h + threshold)
__global__ __launch_bounds__(512) void gemm_kernel(const float* __restrict__ M,
                                                   const _Float16* __restrict__ w16t,
                                                   const _Float16* __restrict__ wrt,
                                                   const float* __restrict__ bias,
                                                   const float* __restrict__ nsv,
                                                   _Float16* __restrict__ outh,
                                                   float* __restrict__ outf,
                                                   float* __restrict__ out2, int n) {
    __shared__ _Float16 A16s[64 * 128];
    __shared__ _Float16 Ars[64 * 128];
    __shared__ _Float16 W16s[128 * 128];
    __shared__ _Float16 Wrs[128 * 128];
    int tid = threadIdx.x;
    int r0 = blockIdx.x * 64;

    // stage W (value+residual), XOR-swizzled 16B chunks: chunk ^= (col&7)
    #pragma unroll
    for (int j = 0; j < 4; ++j) {
        int i = tid + j * 512;             // 2048 float4 per array
        int col = i >> 4, ch = i & 15;
        int d = col * 16 + (ch ^ (col & 7));
        ((float4*)W16s)[d] = ((const float4*)w16t)[i];
        ((float4*)Wrs)[d]  = ((const float4*)wrt)[i];
    }
    // stage A rows r0..r0+63: fp32 -> fp16 value + residual, swizzled
    #pragma unroll
    for (int j = 0; j < 4; ++j) {
        int i = tid + j * 512;             // 2048 float4 of source fp32
        int row = i >> 5, c4 = i & 31;
        int gr = r0 + row;
        float4 v = make_float4(0.f, 0.f, 0.f, 0.f);
        if (gr < n) v = ((const float4*)(M + (size_t)gr * FEAT))[c4];
        half4v h, rr;
        h[0] = (_Float16)v.x; h[1] = (_Float16)v.y; h[2] = (_Float16)v.z; h[3] = (_Float16)v.w;
        rr[0] = (_Float16)(v.x - (float)h[0]); rr[1] = (_Float16)(v.y - (float)h[1]);
        rr[2] = (_Float16)(v.z - (float)h[2]); rr[3] = (_Float16)(v.w - (float)h[3]);
        int d = row * 128 + (((c4 >> 1) ^ (row & 7)) << 3) + ((c4 & 1) << 2);
        *(half4v*)(A16s + d) = h;
        *(half4v*)(Ars + d) = rr;
    }
    __syncthreads();

    int lane = tid & 63;
    int w = tid >> 6;                      // 8 waves: 4 row-groups x 2 col-groups
    int l15 = lane & 15;
    int q = lane >> 4;
    int rw = w & 3, cw = w >> 2;
    int rbase = rw * 16 + l15;             // A-frag row
    int cbase = cw * 64;                   // wave's 64-col strip

    f32x4 acc[4] = {{0.f,0.f,0.f,0.f},{0.f,0.f,0.f,0.f},{0.f,0.f,0.f,0.f},{0.f,0.f,0.f,0.f}};
    #pragma unroll
    for (int ks = 0; ks < 4; ++ks) {
        int chunk = ks * 4 + q;
        int aoff = rbase * 128 + ((chunk ^ (rbase & 7)) << 3);
        half8 a16 = *(const half8*)(A16s + aoff);
        half8 ar  = *(const half8*)(Ars + aoff);
        #pragma unroll
        for (int ct = 0; ct < 4; ++ct) {
            int col = cbase + ct * 16 + l15;
            int boff = col * 128 + ((chunk ^ (col & 7)) << 3);
            half8 b16 = *(const half8*)(W16s + boff);
            half8 br  = *(const half8*)(Wrs + boff);
            acc[ct] = __builtin_amdgcn_mfma_f32_16x16x32_f16(a16, b16, acc[ct], 0, 0, 0);
            acc[ct] = __builtin_amdgcn_mfma_f32_16x16x32_f16(a16, br,  acc[ct], 0, 0, 0);
            acc[ct] = __builtin_amdgcn_mfma_f32_16x16x32_f16(ar,  b16, acc[ct], 0, 0, 0);
        }
    }

    // epilogue: C/D layout col=lane&15, row=(lane>>4)*4+reg
    int rloc = rw * 16 + q * 4;
    float scv[4];
    #pragma unroll
    for (int reg = 0; reg < 4; ++reg) {
        int row = r0 + rloc + reg;
        scv[reg] = (MODE == 0 && row < n) ? nsv[row] : 1.0f;
    }
    #pragma unroll
    for (int ct = 0; ct < 4; ++ct) {
        int col = cbase + ct * 16 + l15;
        float b = bias[col];
        #pragma unroll
        for (int reg = 0; reg < 4; ++reg) {
            int row = r0 + rloc + reg;
            if (row < n) {
                float h = acc[ct][reg] + b;
                h = h > 0.f ? h : 0.f;
                if (MODE == 0) {
                    outh[(size_t)row * FEAT + col] = (_Float16)(h * scv[reg]);
                } else {
                    outf[(size_t)row * FEAT + col] = h;
                    out2[(size_t)row * FEAT + col] = h >= 0.5f ? 1.f : 0.f;
                }
            }
        }
    }
}

extern "C" void kernel_launch(void* const* d_in, const int* in_sizes, int n_in,
                              void* d_out, int out_size, void* d_ws, size_t ws_size,
                              hipStream_t stream) {
    const float* in_feat = (const float*)d_in[0];
    const int*   src     = (const int*)d_in[1];
    const int*   dst     = (const int*)d_in[2];
    const float* W[5] = {(const float*)d_in[3], (const float*)d_in[5], (const float*)d_in[7],
                         (const float*)d_in[9], (const float*)d_in[11]};
    const float* B[5] = {(const float*)d_in[4], (const float*)d_in[6], (const float*)d_in[8],
                         (const float*)d_in[10], (const float*)d_in[12]};
    const int E = in_sizes[1];
    const int N = in_sizes[0] / FEAT;
    const int scanBlocks = (N + 255) / 256;           // 196
    const int NPAD = scanBlocks * 256;                // 50176

    char* ws = (char*)d_ws;
    size_t off = 0;
    auto alloc = [&](size_t bytes) { size_t o = off; off += (bytes + 255) & ~size_t(255); return o; };
    int*      degS     = (int*)(ws + alloc((size_t)NPAD * 4));   // contiguous with degD
    int*      degD     = (int*)(ws + alloc((size_t)NPAD * 4));
    int*      gcursor  = (int*)(ws + alloc((size_t)NPAD * 4));
    int*      esrc     = (int*)(ws + alloc((size_t)E * 4));
    float*    ns       = (float*)(ws + alloc((size_t)N * 4));
    float*    nd       = (float*)(ws + alloc((size_t)N * 4));
    int*      offsc    = (int*)(ws + alloc((size_t)(N + 1) * 4));
    int*      blockSums = (int*)(ws + alloc(1024));
    int*      blockOffs = (int*)(ws + alloc(1024));
    _Float16* w16t     = (_Float16*)(ws + alloc(5 * 16384 * 2));
    _Float16* wrt      = (_Float16*)(ws + alloc(5 * 16384 * 2));
    _Float16* xh       = (_Float16*)(ws + alloc((size_t)N * FEAT * 2));

    float* out_h = (float*)d_out;                     // m scratch; h5 at the end
    float* out_c = out_h + (size_t)N * FEAT;          // threshold output at the end

    const int cnt4 = (2 * NPAD) / 4;                  // degS+degD contiguous
    const int eBlocks = (E + 255) / 256;              // 3125
    zero_kernel<<<(cnt4 + 255) / 256, 256, 0, stream>>>((int4*)degS, cnt4);
    deg_kernel<<<eBlocks, 256, 0, stream>>>(src, dst, degS, degD, E);
    scan1_kernel<<<scanBlocks, 256, 0, stream>>>(degD, degS, blockSums, ns, nd, N);
    scan2_kernel<<<1, 256, 0, stream>>>(blockSums, blockOffs, scanBlocks);
    scan3_kernel<<<scanBlocks, 256, 0, stream>>>(degD, blockOffs, offsc, gcursor, N);
    fill_kernel<<<eBlocks, 256, 0, stream>>>(src, dst, gcursor, esrc, E);
    wprep_kernel<<<320, 256, 0, stream>>>(W[0], W[1], W[2], W[3], W[4], w16t, wrt);
    prescale_kernel<<<(N * (FEAT / 8) + 255) / 256, 256, 0, stream>>>(in_feat, ns, xh, N);

    const int agg_blocks = (int)(((size_t)N * 32 + 255) / 256);   // 6250
    const int gemm_blocks = (N + 63) / 64;                        // 782

    for (int l = 0; l < 5; ++l) {
        agg_kernel<<<agg_blocks, 256, 0, stream>>>(xh, offsc, esrc, nd, out_h, N);
        if (l < 4)
            gemm_kernel<0><<<gemm_blocks, 512, 0, stream>>>(out_h, w16t + (size_t)l * 16384,
                                                            wrt + (size_t)l * 16384, B[l], ns,
                                                            xh, nullptr, nullptr, N);
        else
            gemm_kernel<1><<<gemm_blocks, 512, 0, stream>>>(out_h, w16t + (size_t)l * 16384,
                                                            wrt + (size_t)l * 16384, B[l], nullptr,
                                                            nullptr, out_h, out_c, N);
    }
}